// Round 9
// baseline (104.741 us; speedup 1.0000x reference)
//
#include <hip/hip_runtime.h>
#include <hip/hip_bf16.h>

// QLSTM: T=512, B=256, D_IN=128, D_H=128.
// Gates are per-batch SCALARS broadcast over hidden dim => h,c uniform across
// hidden dim. comb@W[0] = x@W[0][:128] + h*sum(W[0][128:]).
// Pipeline: (1) xz GEMV -> packed float4 (pre-scaled by 1/2pi)  (mem-bound),
//           (2) 512-step scan: 32 blocks x 8 batches. ENTIRE block slice
//               (512x8 float4 = 64KB) staged to LDS up front by 256 threads,
//               then 8 lanes run the serial chain reading LDS only.
//               R6-R8 evidence: global-load register prefetch is always
//               dismantled by the compiler (sunk to use ~200cy exposed) or
//               unsafe via asm (R8 stale-copy corruption). LDS reads are
//               compiler-tracked (correct) and cost ~120cy worst case,
//               amortized by 8-grouped reads per unrolled iteration.
//           (3) broadcast h[t,b] to 128 cols + hx/cx tails (write-bound).

constexpr int T = 512;
constexpr int Bsz = 256;
constexpr int R = T * Bsz;          // 131072 rows
constexpr float INV2PI = 0.15915494309189535f;

// ---------------- Kernel 1: xz[row] = float4(zf,zi,zu,zo)/(2pi), row = t*B+b
__global__ __launch_bounds__(256) void xz_kernel(
    const float* __restrict__ x,
    const float* __restrict__ Wf, const float* __restrict__ bf, const float* __restrict__ tf,
    const float* __restrict__ Wi, const float* __restrict__ bi, const float* __restrict__ ti,
    const float* __restrict__ Wu, const float* __restrict__ bu, const float* __restrict__ tu,
    const float* __restrict__ Wo, const float* __restrict__ bo, const float* __restrict__ to_,
    float4* __restrict__ xz)
{
    const int wglobal = blockIdx.x * 4 + (threadIdx.x >> 6);   // 0..8191
    const int lane = threadIdx.x & 63;
    const int hl = lane & 31;            // lane within half-wave
    const int half = lane >> 5;          // which row of the pair

    const float4 wfv = ((const float4*)Wf)[hl];
    const float4 wiv = ((const float4*)Wi)[hl];
    const float4 wuv = ((const float4*)Wu)[hl];
    const float4 wov = ((const float4*)Wo)[hl];

    const float cf = bf[0] + tf[0];
    const float ci = bi[0] + ti[0];
    const float cu = bu[0] + tu[0];
    const float co = bo[0] + to_[0];

    for (int it = 0; it < 8; ++it) {
        const int row = (it * 8192 + wglobal) * 2 + half;
        const float4 xv = *(const float4*)(x + (size_t)row * 128 + hl * 4);

        float pf = xv.x * wfv.x + xv.y * wfv.y + xv.z * wfv.z + xv.w * wfv.w;
        float pi = xv.x * wiv.x + xv.y * wiv.y + xv.z * wiv.z + xv.w * wiv.w;
        float pu = xv.x * wuv.x + xv.y * wuv.y + xv.z * wuv.z + xv.w * wuv.w;
        float po = xv.x * wov.x + xv.y * wov.y + xv.z * wov.z + xv.w * wov.w;

#pragma unroll
        for (int off = 16; off; off >>= 1) {
            pf += __shfl_xor(pf, off, 64);
            pi += __shfl_xor(pi, off, 64);
            pu += __shfl_xor(pu, off, 64);
            po += __shfl_xor(po, off, 64);
        }
        if (hl == 0) {
            xz[row] = make_float4((pf + cf) * INV2PI, (pi + ci) * INV2PI,
                                  (pu + cu) * INV2PI, (po + co) * INV2PI);
        }
    }
}

// ---------------- Kernel 2: sequential scan, LDS-staged full slice.
// tanh(c), |c|<=~2.1: Pade[5/4] c(945+105c^2+c^4)/(945+420c^2+15c^4), err ~2e-5.
__device__ __forceinline__ float tanh_p54(float c) {
    const float c2 = c * c;
    const float c4 = c2 * c2;
    const float num = fmaf(c2, 105.0f, 945.0f) + c4;
    const float den = fmaf(c4, 15.0f, fmaf(c2, 420.0f, 945.0f));
    return c * num * __builtin_amdgcn_rcpf(den);
}
// sigmoid(cos-arg v), |v|<=1: 0.5 + 0.5*tanh(v/2), odd deg-7 folded (err ~1e-5).
__device__ __forceinline__ float sigp(float v) {
    const float v2 = v * v;
    float p = fmaf(v2, -0.000108281f, 0.00188244f);
    p = fmaf(v2, p, -0.0206916f);
    p = fmaf(v2, p, 0.249976f);
    return fmaf(v, p, 0.5f);
}
// tanh(v), |v|<=1: odd deg-7 (err ~3e-4).
__device__ __forceinline__ float tanp(float v) {
    const float v2 = v * v;
    float p = fmaf(v2, -0.0277200f, 0.120476f);
    p = fmaf(v2, p, -0.331066f);
    p = fmaf(v2, p, 0.999904f);
    return v * p;
}

__device__ __forceinline__ float wsum(const float* __restrict__ W, int lane) {
    float s = W[128 + lane] + W[192 + lane];
#pragma unroll
    for (int off = 32; off; off >>= 1) s += __shfl_xor(s, off, 64);
    return s;  // butterfly: all lanes hold the sum
}

constexpr int BPB = 8;                   // batches per scan block
constexpr int SCAN_BLOCKS = Bsz / BPB;   // 32

__global__ __launch_bounds__(256, 1) void scan_kernel(
    const float4* __restrict__ xz,
    const float* __restrict__ Wf, const float* __restrict__ Wi,
    const float* __restrict__ Wu, const float* __restrict__ Wo,
    float* __restrict__ hscan, float* __restrict__ cfin)
{
    __shared__ float4 lds4[T * BPB];     // 64 KB, layout [t][bg]
    const int tid = threadIdx.x;
    const int bb = blockIdx.x * BPB;

    // ---- stage the entire block slice: 256 threads x 16 float4 loads
#pragma unroll
    for (int k = 0; k < T * BPB / 256; ++k) {      // 16 iterations
        const int j = k * 256 + tid;               // 0..4095
        lds4[j] = xz[(j >> 3) * Bsz + bb + (j & 7)];
    }

    // ---- per-gate hidden-weight sums (wave-wide butterfly, every wave)
    const int l = tid & 63;
    const float swf = wsum(Wf, l) * INV2PI;
    const float swi = wsum(Wi, l) * INV2PI;
    const float swu = wsum(Wu, l) * INV2PI;
    const float swo = wsum(Wo, l) * INV2PI;

    __syncthreads();
    if (tid >= BPB) return;              // lanes 0..7 of wave 0 scan

    const int batch = bb + l;
    const float4* zl = lds4 + l;         // [t][bg=l]: element t at zl[t*BPB]
    float* hp = hscan + batch;

    // carried state: c, tc = tanh(c), os_g = o * sw_g   (h = o*tc only for store)
    float c = 0.0f, tc = 0.0f;
    float osf = 0.0f, osi = 0.0f, osu = 0.0f, oso = 0.0f;

#define QSTEP(Z)                                                  \
    {                                                             \
        const float uf = fmaf(tc, osf, (Z).x);                    \
        const float ui = fmaf(tc, osi, (Z).y);                    \
        const float uu = fmaf(tc, osu, (Z).z);                    \
        const float uo = fmaf(tc, oso, (Z).w);                    \
        const float vf = __builtin_amdgcn_cosf(uf);               \
        const float vi = __builtin_amdgcn_cosf(ui);               \
        const float vu = __builtin_amdgcn_cosf(uu);               \
        const float vo = __builtin_amdgcn_cosf(uo);               \
        const float f  = sigp(vf);                                \
        const float i  = sigp(vi);                                \
        const float o  = sigp(vo);                                \
        const float g  = tanp(vu);                                \
        c  = fmaf(f, c, i * g);                                   \
        tc = tanh_p54(c);                                         \
        osf = o * swf; osi = o * swi;                             \
        osu = o * swu; oso = o * swo;                             \
        *hp = o * tc;                                             \
        hp += Bsz;                                                \
    }

    // 8 grouped LDS reads at the top of each iteration (named vars), then
    // 8 serial steps: the compiler can satisfy uses with incremental lgkmcnt.
    for (int tb = 0; tb < T; tb += 8) {
        const float4* zt = zl + (size_t)tb * BPB;
        const float4 y0 = zt[0 * BPB];
        const float4 y1 = zt[1 * BPB];
        const float4 y2 = zt[2 * BPB];
        const float4 y3 = zt[3 * BPB];
        const float4 y4 = zt[4 * BPB];
        const float4 y5 = zt[5 * BPB];
        const float4 y6 = zt[6 * BPB];
        const float4 y7 = zt[7 * BPB];
        QSTEP(y0); QSTEP(y1); QSTEP(y2); QSTEP(y3);
        QSTEP(y4); QSTEP(y5); QSTEP(y6); QSTEP(y7);
    }
#undef QSTEP

    cfin[batch] = c;
}

// ---------------- Kernel 3: broadcast h[t,b] across 128 hidden cols, + hx/cx tails.
__global__ __launch_bounds__(256) void bcast_kernel(
    const float* __restrict__ hscan, const float* __restrict__ cfin,
    float4* __restrict__ out)
{
    const unsigned i = blockIdx.x * 256u + threadIdx.x;  // float4 index
    const unsigned row = i >> 5;                          // output row (128 floats)
    float v;
    if (row < (unsigned)R) {
        v = hscan[row];
    } else {
        const unsigned r2 = row - (unsigned)R;
        v = (r2 < (unsigned)Bsz) ? hscan[(T - 1) * Bsz + r2] : cfin[r2 - (unsigned)Bsz];
    }
    out[i] = make_float4(v, v, v, v);
}

extern "C" void kernel_launch(void* const* d_in, const int* in_sizes, int n_in,
                              void* d_out, int out_size, void* d_ws, size_t ws_size,
                              hipStream_t stream)
{
    const float* x  = (const float*)d_in[0];
    const float* Wf = (const float*)d_in[1];
    const float* bf = (const float*)d_in[2];
    const float* tf = (const float*)d_in[3];
    const float* Wi = (const float*)d_in[4];
    const float* bi = (const float*)d_in[5];
    const float* ti = (const float*)d_in[6];
    const float* Wu = (const float*)d_in[7];
    const float* bu = (const float*)d_in[8];
    const float* tu = (const float*)d_in[9];
    const float* Wo = (const float*)d_in[10];
    const float* bo = (const float*)d_in[11];
    const float* to_ = (const float*)d_in[12];

    float* ws    = (float*)d_ws;
    float4* xz   = (float4*)ws;       // R float4s  (4*R floats)
    float* hscan = ws + 4 * R;        // R floats
    float* cfin  = ws + 5 * R;        // Bsz floats

    xz_kernel<<<2048, 256, 0, stream>>>(x, Wf, bf, tf, Wi, bi, ti, Wu, bu, tu, Wo, bo, to_, xz);
    scan_kernel<<<SCAN_BLOCKS, 256, 0, stream>>>(xz, Wf, Wi, Wu, Wo, hscan, cfin);

    const int total_f4 = (R + 2 * Bsz) * 32;              // 4,210,688
    bcast_kernel<<<total_f4 / 256, 256, 0, stream>>>(hscan, cfin, (float4*)d_out);
}

// Round 10
// 91.925 us; speedup vs baseline: 1.1394x; 1.1394x over previous
//
#include <hip/hip_runtime.h>
#include <hip/hip_bf16.h>

// QLSTM: T=512, B=256, D_IN=128, D_H=128.
// Gates are per-batch SCALARS broadcast over hidden dim => h,c uniform across
// hidden dim. comb@W[0] = x@W[0][:128] + h*sum(W[0][128:]).
// R9 post-mortem: scan is ISSUE+CHAIN bound (51% issue-busy per active SIMD;
// ~45 VALU + 5 quarter-rate trans per step). R10: same structure, lean math:
// no rcp in the loop (poly tanh), deg-5 sigmoid, h-carried form.

constexpr int T = 512;
constexpr int Bsz = 256;
constexpr int R = T * Bsz;          // 131072 rows
constexpr float INV2PI = 0.15915494309189535f;

// ---------------- Kernel 1: xz[row] = float4(zf,zi,zu,zo)/(2pi), row = t*B+b
__global__ __launch_bounds__(256) void xz_kernel(
    const float* __restrict__ x,
    const float* __restrict__ Wf, const float* __restrict__ bf, const float* __restrict__ tf,
    const float* __restrict__ Wi, const float* __restrict__ bi, const float* __restrict__ ti,
    const float* __restrict__ Wu, const float* __restrict__ bu, const float* __restrict__ tu,
    const float* __restrict__ Wo, const float* __restrict__ bo, const float* __restrict__ to_,
    float4* __restrict__ xz)
{
    const int wglobal = blockIdx.x * 4 + (threadIdx.x >> 6);   // 0..8191
    const int lane = threadIdx.x & 63;
    const int hl = lane & 31;            // lane within half-wave
    const int half = lane >> 5;          // which row of the pair

    const float4 wfv = ((const float4*)Wf)[hl];
    const float4 wiv = ((const float4*)Wi)[hl];
    const float4 wuv = ((const float4*)Wu)[hl];
    const float4 wov = ((const float4*)Wo)[hl];

    const float cf = bf[0] + tf[0];
    const float ci = bi[0] + ti[0];
    const float cu = bu[0] + tu[0];
    const float co = bo[0] + to_[0];

    for (int it = 0; it < 8; ++it) {
        const int row = (it * 8192 + wglobal) * 2 + half;
        const float4 xv = *(const float4*)(x + (size_t)row * 128 + hl * 4);

        float pf = xv.x * wfv.x + xv.y * wfv.y + xv.z * wfv.z + xv.w * wfv.w;
        float pi = xv.x * wiv.x + xv.y * wiv.y + xv.z * wiv.z + xv.w * wiv.w;
        float pu = xv.x * wuv.x + xv.y * wuv.y + xv.z * wuv.z + xv.w * wuv.w;
        float po = xv.x * wov.x + xv.y * wov.y + xv.z * wov.z + xv.w * wov.w;

#pragma unroll
        for (int off = 16; off; off >>= 1) {
            pf += __shfl_xor(pf, off, 64);
            pi += __shfl_xor(pi, off, 64);
            pu += __shfl_xor(pu, off, 64);
            po += __shfl_xor(po, off, 64);
        }
        if (hl == 0) {
            xz[row] = make_float4((pf + cf) * INV2PI, (pi + ci) * INV2PI,
                                  (pu + cu) * INV2PI, (po + co) * INV2PI);
        }
    }
}

// ---------------- Kernel 2: sequential scan, LDS-staged full slice.
// sigmoid(v)=0.5+0.5*tanh(v/2) folded, |v|<=1, odd deg-5 (err ~1.1e-4).
__device__ __forceinline__ float sigp5(float v) {
    const float v2 = v * v;
    float p = fmaf(v2, 0.00188244f, -0.0206916f);
    p = fmaf(v2, p, 0.249976f);
    return fmaf(v, p, 0.5f);
}
// tanh(v), |v|<=1: odd deg-7 (err ~3e-4).
__device__ __forceinline__ float tanp(float v) {
    const float v2 = v * v;
    float p = fmaf(v2, -0.0277200f, 0.120476f);
    p = fmaf(v2, p, -0.331066f);
    p = fmaf(v2, p, 0.999904f);
    return v * p;
}
// tanh(c), |c|<=2.07 (provable bound): odd deg-9 POLYNOMIAL (no rcp!),
// interpolated at x={0.3,0.8,1.3,1.75,2.05}; err ~1e-3 typ, <=5e-3 near end.
__device__ __forceinline__ float tanh9(float c) {
    const float y  = c * c;
    const float y2 = y * y;
    const float lo  = fmaf(y, -0.321470f, 0.999168f);
    const float hi  = fmaf(y, 0.0016407f, -0.0199491f);
    const float mid = fmaf(y, hi, 0.101498f);
    return c * fmaf(y2, mid, lo);
}

__device__ __forceinline__ float wsum(const float* __restrict__ W, int lane) {
    float s = W[128 + lane] + W[192 + lane];
#pragma unroll
    for (int off = 32; off; off >>= 1) s += __shfl_xor(s, off, 64);
    return s;  // butterfly: all lanes hold the sum
}

constexpr int BPB = 8;                   // batches per scan block
constexpr int SCAN_BLOCKS = Bsz / BPB;   // 32

__global__ __launch_bounds__(256, 1) void scan_kernel(
    const float4* __restrict__ xz,
    const float* __restrict__ Wf, const float* __restrict__ Wi,
    const float* __restrict__ Wu, const float* __restrict__ Wo,
    float* __restrict__ hscan, float* __restrict__ cfin)
{
    __shared__ float4 lds4[T * BPB];     // 64 KB, layout [t][bg]
    const int tid = threadIdx.x;
    const int bb = blockIdx.x * BPB;

    // ---- stage the entire block slice: 256 threads x 16 float4 loads
#pragma unroll
    for (int k = 0; k < T * BPB / 256; ++k) {      // 16 iterations
        const int j = k * 256 + tid;               // 0..4095
        lds4[j] = xz[(j >> 3) * Bsz + bb + (j & 7)];
    }

    // ---- per-gate hidden-weight sums (wave-wide butterfly, every wave)
    const int l = tid & 63;
    const float swf = wsum(Wf, l) * INV2PI;
    const float swi = wsum(Wi, l) * INV2PI;
    const float swu = wsum(Wu, l) * INV2PI;
    const float swo = wsum(Wo, l) * INV2PI;

    __syncthreads();
    if (tid >= BPB) return;              // lanes 0..7 of wave 0 scan

    const int batch = bb + l;
    const float4* zl = lds4 + l;         // [t][bg=l]: element t at zl[t*BPB]
    float* hp = hscan + batch;

    float h = 0.0f, c = 0.0f;

#define QSTEP(Z)                                                  \
    {                                                             \
        const float uf = fmaf(h, swf, (Z).x);                     \
        const float ui = fmaf(h, swi, (Z).y);                     \
        const float uu = fmaf(h, swu, (Z).z);                     \
        const float uo = fmaf(h, swo, (Z).w);                     \
        const float vf = __builtin_amdgcn_cosf(uf);               \
        const float vi = __builtin_amdgcn_cosf(ui);               \
        const float vu = __builtin_amdgcn_cosf(uu);               \
        const float vo = __builtin_amdgcn_cosf(uo);               \
        const float f  = sigp5(vf);                               \
        const float i  = sigp5(vi);                               \
        const float o  = sigp5(vo);                               \
        const float g  = tanp(vu);                                \
        c = fmaf(f, c, i * g);                                    \
        h = o * tanh9(c);                                         \
        *hp = h;                                                  \
        hp += Bsz;                                                \
    }

    // 8 grouped LDS reads at the top of each iteration (named vars), then
    // 8 serial steps: incremental lgkmcnt satisfies uses.
    for (int tb = 0; tb < T; tb += 8) {
        const float4* zt = zl + (size_t)tb * BPB;
        const float4 y0 = zt[0 * BPB];
        const float4 y1 = zt[1 * BPB];
        const float4 y2 = zt[2 * BPB];
        const float4 y3 = zt[3 * BPB];
        const float4 y4 = zt[4 * BPB];
        const float4 y5 = zt[5 * BPB];
        const float4 y6 = zt[6 * BPB];
        const float4 y7 = zt[7 * BPB];
        QSTEP(y0); QSTEP(y1); QSTEP(y2); QSTEP(y3);
        QSTEP(y4); QSTEP(y5); QSTEP(y6); QSTEP(y7);
    }
#undef QSTEP

    cfin[batch] = c;
}

// ---------------- Kernel 3: broadcast h[t,b] across 128 hidden cols, + hx/cx tails.
__global__ __launch_bounds__(256) void bcast_kernel(
    const float* __restrict__ hscan, const float* __restrict__ cfin,
    float4* __restrict__ out)
{
    const unsigned i = blockIdx.x * 256u + threadIdx.x;  // float4 index
    const unsigned row = i >> 5;                          // output row (128 floats)
    float v;
    if (row < (unsigned)R) {
        v = hscan[row];
    } else {
        const unsigned r2 = row - (unsigned)R;
        v = (r2 < (unsigned)Bsz) ? hscan[(T - 1) * Bsz + r2] : cfin[r2 - (unsigned)Bsz];
    }
    out[i] = make_float4(v, v, v, v);
}

extern "C" void kernel_launch(void* const* d_in, const int* in_sizes, int n_in,
                              void* d_out, int out_size, void* d_ws, size_t ws_size,
                              hipStream_t stream)
{
    const float* x  = (const float*)d_in[0];
    const float* Wf = (const float*)d_in[1];
    const float* bf = (const float*)d_in[2];
    const float* tf = (const float*)d_in[3];
    const float* Wi = (const float*)d_in[4];
    const float* bi = (const float*)d_in[5];
    const float* ti = (const float*)d_in[6];
    const float* Wu = (const float*)d_in[7];
    const float* bu = (const float*)d_in[8];
    const float* tu = (const float*)d_in[9];
    const float* Wo = (const float*)d_in[10];
    const float* bo = (const float*)d_in[11];
    const float* to_ = (const float*)d_in[12];

    float* ws    = (float*)d_ws;
    float4* xz   = (float4*)ws;       // R float4s  (4*R floats)
    float* hscan = ws + 4 * R;        // R floats
    float* cfin  = ws + 5 * R;        // Bsz floats

    xz_kernel<<<2048, 256, 0, stream>>>(x, Wf, bf, tf, Wi, bi, ti, Wu, bu, tu, Wo, bo, to_, xz);
    scan_kernel<<<SCAN_BLOCKS, 256, 0, stream>>>(xz, Wf, Wi, Wu, Wo, hscan, cfin);

    const int total_f4 = (R + 2 * Bsz) * 32;              // 4,210,688
    bcast_kernel<<<total_f4 / 256, 256, 0, stream>>>(hscan, cfin, (float4*)d_out);
}

// Round 11
// 73.797 us; speedup vs baseline: 1.4193x; 1.2456x over previous
//
#include <hip/hip_runtime.h>
#include <hip/hip_bf16.h>

// QLSTM: T=512, B=256, D_IN=128, D_H=128.
// Gates are per-batch SCALARS broadcast over hidden dim => h,c uniform across
// hidden dim. comb@W[0] = x@W[0][:128] + h*sum(W[0][128:]).
// R10 post-mortem: single-wave scan wall = issue (143cy) + exposed chain
// (140cy), additive. R11: R9's LDS-staged skeleton + R4's 4-lanes-per-batch
// gate split (issue/4, DPP quad_perm exchange), unified per-lane poly.

constexpr int T = 512;
constexpr int Bsz = 256;
constexpr int R = T * Bsz;          // 131072 rows
constexpr float INV2PI = 0.15915494309189535f;

// ---------------- Kernel 1: xz[row] = float4(zf,zi,zu,zo)/(2pi), row = t*B+b
__global__ __launch_bounds__(256) void xz_kernel(
    const float* __restrict__ x,
    const float* __restrict__ Wf, const float* __restrict__ bf, const float* __restrict__ tf,
    const float* __restrict__ Wi, const float* __restrict__ bi, const float* __restrict__ ti,
    const float* __restrict__ Wu, const float* __restrict__ bu, const float* __restrict__ tu,
    const float* __restrict__ Wo, const float* __restrict__ bo, const float* __restrict__ to_,
    float4* __restrict__ xz)
{
    const int wglobal = blockIdx.x * 4 + (threadIdx.x >> 6);   // 0..8191
    const int lane = threadIdx.x & 63;
    const int hl = lane & 31;            // lane within half-wave
    const int half = lane >> 5;          // which row of the pair

    const float4 wfv = ((const float4*)Wf)[hl];
    const float4 wiv = ((const float4*)Wi)[hl];
    const float4 wuv = ((const float4*)Wu)[hl];
    const float4 wov = ((const float4*)Wo)[hl];

    const float cf = bf[0] + tf[0];
    const float ci = bi[0] + ti[0];
    const float cu = bu[0] + tu[0];
    const float co = bo[0] + to_[0];

    for (int it = 0; it < 8; ++it) {
        const int row = (it * 8192 + wglobal) * 2 + half;
        const float4 xv = *(const float4*)(x + (size_t)row * 128 + hl * 4);

        float pf = xv.x * wfv.x + xv.y * wfv.y + xv.z * wfv.z + xv.w * wfv.w;
        float pi = xv.x * wiv.x + xv.y * wiv.y + xv.z * wiv.z + xv.w * wiv.w;
        float pu = xv.x * wuv.x + xv.y * wuv.y + xv.z * wuv.z + xv.w * wuv.w;
        float po = xv.x * wov.x + xv.y * wov.y + xv.z * wov.z + xv.w * wov.w;

#pragma unroll
        for (int off = 16; off; off >>= 1) {
            pf += __shfl_xor(pf, off, 64);
            pi += __shfl_xor(pi, off, 64);
            pu += __shfl_xor(pu, off, 64);
            po += __shfl_xor(po, off, 64);
        }
        if (hl == 0) {
            xz[row] = make_float4((pf + cf) * INV2PI, (pi + ci) * INV2PI,
                                  (pu + cu) * INV2PI, (po + co) * INV2PI);
        }
    }
}

// ---------------- Kernel 2: sequential scan, LDS-staged, 4 lanes per batch.
// tanh(c), |c|<=2.07 (provable bound): odd deg-9 polynomial (no rcp),
// err ~1e-3 typ, <=5e-3 near endpoint.
__device__ __forceinline__ float tanh9(float c) {
    const float y  = c * c;
    const float y2 = y * y;
    const float lo  = fmaf(y, -0.321470f, 0.999168f);
    const float hi  = fmaf(y, 0.0016407f, -0.0199491f);
    const float mid = fmaf(y, hi, 0.101498f);
    return c * fmaf(y2, mid, lo);
}

template<int CTRL>
__device__ __forceinline__ float dppq(float x) {
    return __builtin_bit_cast(float,
        __builtin_amdgcn_mov_dpp(__builtin_bit_cast(int, x), CTRL, 0xF, 0xF, true));
}

__device__ __forceinline__ float wsum(const float* __restrict__ W, int lane) {
    float s = W[128 + lane] + W[192 + lane];
#pragma unroll
    for (int off = 32; off; off >>= 1) s += __shfl_xor(s, off, 64);
    return s;  // butterfly: all lanes hold the sum
}

constexpr int BPB = 8;                   // batches per scan block
constexpr int SCAN_BLOCKS = Bsz / BPB;   // 32

__global__ __launch_bounds__(256, 1) void scan_kernel(
    const float4* __restrict__ xz,
    const float* __restrict__ Wf, const float* __restrict__ Wi,
    const float* __restrict__ Wu, const float* __restrict__ Wo,
    float* __restrict__ hscan, float* __restrict__ cfin)
{
    __shared__ float4 lds4[T * BPB];     // 64 KB, layout [t][bg] float4=4 gates
    const int tid = threadIdx.x;
    const int bb = blockIdx.x * BPB;

    // ---- stage the entire block slice: 256 threads x 16 float4 loads
#pragma unroll
    for (int k = 0; k < T * BPB / 256; ++k) {      // 16 iterations
        const int j = k * 256 + tid;               // 0..4095
        lds4[j] = xz[(j >> 3) * Bsz + bb + (j & 7)];
    }

    // ---- per-gate hidden-weight sums (wave-wide butterfly, every wave)
    const int l = tid & 63;
    const float swf = wsum(Wf, l) * INV2PI;
    const float swi = wsum(Wi, l) * INV2PI;
    const float swu = wsum(Wu, l) * INV2PI;
    const float swo = wsum(Wo, l) * INV2PI;

    __syncthreads();
    if (tid >= BPB * 4) return;          // lanes 0..31 of wave 0 scan

    const int q = tid & 3;               // gate: 0=f 1=i 2=g(tanh) 3=o
    const int bg = tid >> 2;             // batch-in-block 0..7
    const int batch = bb + bg;

    // this lane's gate row-sum (already *INV2PI)
    const float sw = (q == 0) ? swf : (q == 1) ? swi : (q == 2) ? swu : swo;

    // unified odd deg-7 gate polynomial in v = cos(u):
    //   tanh lane (q==2): tanh(v); sigmoid lanes: 0.5 + 0.5*tanh(v/2) (folded).
    const bool tq = (q == 2);
    const float K0 = tq ? 0.0f        : 0.5f;
    const float K1 = tq ? 0.999904f   : 0.249976f;
    const float K3 = tq ? -0.331066f  : -0.0206916f;
    const float K5 = tq ? 0.120476f   : 0.00188244f;
    const float K7 = tq ? -0.0277200f : -0.000108281f;

    const float* zl = (const float*)lds4 + tid;   // scalar [t*32 + bg*4 + q]
    float* hp = hscan + batch;                    // all 4 quad lanes store same h

    float h = 0.0f, c = 0.0f;

#define QSTEP(Z)                                                  \
    {                                                             \
        const float u  = fmaf(h, sw, (Z));                        \
        const float v  = __builtin_amdgcn_cosf(u);                \
        const float v2 = v * v;                                   \
        const float v4 = v2 * v2;                                 \
        const float ph = fmaf(v2, K7, K5);                        \
        const float pl = fmaf(v2, K3, K1);                        \
        const float gown = fmaf(v, fmaf(v4, ph, pl), K0);         \
        const float f = dppq<0x00>(gown);                         \
        const float i = dppq<0x55>(gown);                         \
        const float g = dppq<0xAA>(gown);                         \
        const float o = dppq<0xFF>(gown);                         \
        c = fmaf(f, c, i * g);                                    \
        h = o * tanh9(c);                                         \
        *hp = h;                                                  \
        hp += Bsz;                                                \
    }

    // 8 grouped conflict-free ds_read_b32 (bank = lane), then 8 serial steps.
    for (int tb = 0; tb < T; tb += 8) {
        const float* zt = zl + (size_t)tb * 32;
        const float y0 = zt[0 * 32];
        const float y1 = zt[1 * 32];
        const float y2 = zt[2 * 32];
        const float y3 = zt[3 * 32];
        const float y4 = zt[4 * 32];
        const float y5 = zt[5 * 32];
        const float y6 = zt[6 * 32];
        const float y7 = zt[7 * 32];
        QSTEP(y0); QSTEP(y1); QSTEP(y2); QSTEP(y3);
        QSTEP(y4); QSTEP(y5); QSTEP(y6); QSTEP(y7);
    }
#undef QSTEP

    cfin[batch] = c;                     // 4 lanes, same value, same addr
}

// ---------------- Kernel 3: broadcast h[t,b] across 128 hidden cols, + hx/cx tails.
__global__ __launch_bounds__(256) void bcast_kernel(
    const float* __restrict__ hscan, const float* __restrict__ cfin,
    float4* __restrict__ out)
{
    const unsigned i = blockIdx.x * 256u + threadIdx.x;  // float4 index
    const unsigned row = i >> 5;                          // output row (128 floats)
    float v;
    if (row < (unsigned)R) {
        v = hscan[row];
    } else {
        const unsigned r2 = row - (unsigned)R;
        v = (r2 < (unsigned)Bsz) ? hscan[(T - 1) * Bsz + r2] : cfin[r2 - (unsigned)Bsz];
    }
    out[i] = make_float4(v, v, v, v);
}

extern "C" void kernel_launch(void* const* d_in, const int* in_sizes, int n_in,
                              void* d_out, int out_size, void* d_ws, size_t ws_size,
                              hipStream_t stream)
{
    const float* x  = (const float*)d_in[0];
    const float* Wf = (const float*)d_in[1];
    const float* bf = (const float*)d_in[2];
    const float* tf = (const float*)d_in[3];
    const float* Wi = (const float*)d_in[4];
    const float* bi = (const float*)d_in[5];
    const float* ti = (const float*)d_in[6];
    const float* Wu = (const float*)d_in[7];
    const float* bu = (const float*)d_in[8];
    const float* tu = (const float*)d_in[9];
    const float* Wo = (const float*)d_in[10];
    const float* bo = (const float*)d_in[11];
    const float* to_ = (const float*)d_in[12];

    float* ws    = (float*)d_ws;
    float4* xz   = (float4*)ws;       // R float4s  (4*R floats)
    float* hscan = ws + 4 * R;        // R floats
    float* cfin  = ws + 5 * R;        // Bsz floats

    xz_kernel<<<2048, 256, 0, stream>>>(x, Wf, bf, tf, Wi, bi, ti, Wu, bu, tu, Wo, bo, to_, xz);
    scan_kernel<<<SCAN_BLOCKS, 256, 0, stream>>>(xz, Wf, Wi, Wu, Wo, hscan, cfin);

    const int total_f4 = (R + 2 * Bsz) * 32;              // 4,210,688
    bcast_kernel<<<total_f4 / 256, 256, 0, stream>>>(hscan, cfin, (float4*)d_out);
}